// Round 1
// baseline (263.674 us; speedup 1.0000x reference)
//
#include <hip/hip_runtime.h>
#include <hip/hip_bf16.h>
#include <math.h>

#define HWSZ 36864            // 192*192
#define NTILE 576             // HWSZ / 64
#define NBLK 1152             // B * NTILE

// ---------------- precompute 1: Dmat[s][d][c] = adapt_w[s][d][c] / sigma[s][d]
__global__ void pre_dmat(const float* __restrict__ aw, const float* __restrict__ sigma,
                         float* __restrict__ Dmat) {
    int idx = blockIdx.x * 256 + threadIdx.x;
    if (idx < 20480) {
        int sd = idx >> 6;              // s*64 + d
        Dmat[idx] = aw[idx] / sigma[sd];
    }
}

// ---------------- precompute 2: folded MLP weights
// M_T[o][s][c]  = sum_d (w1[o,s*192+64+d] + w1[o,s*192+128+d]) * Dmat[s][d][c]
// M_Sp[o][c]    = sum_{s,d} (w1[o,s*192+d] + w1[o,s*192+64+d]) * Dmat[s][d][c]
// c1[o]         = r_b1[o] + sum_{s,d} (w1[o,s*192+d]+w1[o,s*192+64+d]) * (ab[s,d]-mu[s,d])/sigma[s,d]
__global__ void pre_weights(const float* __restrict__ rw1, const float* __restrict__ rb1,
                            const float* __restrict__ ab, const float* __restrict__ mu,
                            const float* __restrict__ sigma, const float* __restrict__ Dmat,
                            float* __restrict__ M_T, float* __restrict__ M_Sp,
                            float* __restrict__ c1) {
    int idx = blockIdx.x * 256 + threadIdx.x;
    if (idx < 20480) {
        int o = idx / 320, r = idx % 320, s = r >> 6, c = r & 63;
        float sum = 0.f;
        const float* w = rw1 + o * 960 + s * 192;
        const float* D = Dmat + s * 4096 + c;
        #pragma unroll 8
        for (int d = 0; d < 64; ++d)
            sum = fmaf(w[64 + d] + w[128 + d], D[d * 64], sum);
        M_T[idx] = sum;
    } else if (idx < 24576) {
        int k = idx - 20480;
        int o = k >> 6, c = k & 63;
        float sum = 0.f;
        for (int s = 0; s < 5; ++s) {
            const float* w = rw1 + o * 960 + s * 192;
            const float* D = Dmat + s * 4096 + c;
            #pragma unroll 8
            for (int d = 0; d < 64; ++d)
                sum = fmaf(w[d] + w[64 + d], D[d * 64], sum);
        }
        M_Sp[k] = sum;
    } else if (idx < 24640) {
        int o = idx - 24576;
        float sum = rb1[o];
        for (int s = 0; s < 5; ++s) {
            const float* w = rw1 + o * 960 + s * 192;
            #pragma unroll 8
            for (int d = 0; d < 64; ++d) {
                int sd = s * 64 + d;
                sum = fmaf(w[d] + w[64 + d], (ab[sd] - mu[sd]) / sigma[sd], sum);
            }
        }
        c1[o] = sum;
    }
}

// ---------------- fused main: per 64-pixel tile
// computes delta_s = D_s X_s, proxy partial sums, h = relu(c1 + M_Sp S + sum_s M_Ts X_s),
// score_learn = r_w2 h + r_b2
__global__ __launch_bounds__(256) void fused_main(
        const float* __restrict__ S, const float* __restrict__ T,
        const float* __restrict__ Dmat, const float* __restrict__ M_T,
        const float* __restrict__ M_Sp, const float* __restrict__ c1,
        const float* __restrict__ rw2, const float* __restrict__ rb2,
        float* __restrict__ slearn, float* __restrict__ partial) {
    __shared__ float Sx[64][64];   // S tile, later reused as relu(h) buffer
    __shared__ float Xs[64][64];   // (T_s - S) tile
    __shared__ float wsum[5][4];

    const int tid = threadIdx.x;
    const int p   = tid & 63;      // pixel within tile
    const int dq  = tid >> 6;      // output quarter 0..3
    const int dqu = __builtin_amdgcn_readfirstlane(dq);  // wave-uniform -> scalar loads
    const int blk = blockIdx.x;
    const int b    = blk / NTILE;
    const int pix0 = (blk % NTILE) * 64;

    // stage S tile (coalesced float4)
    for (int idx = tid; idx < 1024; idx += 256) {
        int c = idx >> 4, q = idx & 15;
        float4 v = *reinterpret_cast<const float4*>(S + ((size_t)(b * 64 + c)) * HWSZ + pix0 + q * 4);
        *reinterpret_cast<float4*>(&Sx[c][q * 4]) = v;
    }
    __syncthreads();

    // h accumulator: c1 + M_Sp @ S
    float acch[16];
    #pragma unroll
    for (int j = 0; j < 16; ++j) acch[j] = c1[dqu * 16 + j];
    {
        const float* Wp = M_Sp + dqu * 16 * 64;
        #pragma unroll 4
        for (int c = 0; c < 64; ++c) {
            float xc = Sx[c][p];
            #pragma unroll
            for (int j = 0; j < 16; ++j) acch[j] = fmaf(Wp[j * 64 + c], xc, acch[j]);
        }
    }

    for (int s = 0; s < 5; ++s) {
        __syncthreads();
        // stage X = T_s - S
        for (int idx = tid; idx < 1024; idx += 256) {
            int c = idx >> 4, q = idx & 15;
            float4 v = *reinterpret_cast<const float4*>(
                T + ((size_t)((b * 5 + s) * 64 + c)) * HWSZ + pix0 + q * 4);
            float4 sv = *reinterpret_cast<const float4*>(&Sx[c][q * 4]);
            float4 x; x.x = v.x - sv.x; x.y = v.y - sv.y; x.z = v.z - sv.z; x.w = v.w - sv.w;
            *reinterpret_cast<float4*>(&Xs[c][q * 4]) = x;
        }
        __syncthreads();

        float accd[16];
        #pragma unroll
        for (int j = 0; j < 16; ++j) accd[j] = 0.f;
        const float* Dp = Dmat + s * 4096 + dqu * 16 * 64;   // [j][c] stride 64
        const float* Mp = M_T + (dqu * 16) * 320 + s * 64;   // [j][c] stride 320
        #pragma unroll 4
        for (int c = 0; c < 64; ++c) {
            float xc = Xs[c][p];
            #pragma unroll
            for (int j = 0; j < 16; ++j) accd[j] = fmaf(Dp[j * 64 + c], xc, accd[j]);
            #pragma unroll
            for (int j = 0; j < 16; ++j) acch[j] = fmaf(Mp[j * 320 + c], xc, acch[j]);
        }
        // proxy partial: sum_d delta^2 over this thread's quarter, then wave-reduce over pixels
        float ps = 0.f;
        #pragma unroll
        for (int j = 0; j < 16; ++j) ps = fmaf(accd[j], accd[j], ps);
        #pragma unroll
        for (int m = 1; m < 64; m <<= 1) ps += __shfl_xor(ps, m, 64);
        if (p == 0) wsum[s][dq] = ps;
    }
    __syncthreads();

    if (tid < 5)
        partial[blk * 5 + tid] = wsum[tid][0] + wsum[tid][1] + wsum[tid][2] + wsum[tid][3];

    // relu(h) -> reuse Sx as [o][p]
    #pragma unroll
    for (int j = 0; j < 16; ++j) Sx[dqu * 16 + j][p] = fmaxf(acch[j], 0.f);
    __syncthreads();

    // score_learn = r_w2 @ h + r_b2
    for (int sp = dq; sp < 5; sp += 4) {
        float sum = rb2[sp];
        #pragma unroll 4
        for (int o = 0; o < 64; ++o) sum = fmaf(rw2[sp * 64 + o], Sx[o][p], sum);
        slearn[((size_t)(b * 5 + sp)) * HWSZ + pix0 + p] = sum;
    }
}

// ---------------- reduce proxy partials -> per-s score (deterministic)
__global__ void score_kernel(const float* __restrict__ partial,
                             const float* __restrict__ ema_proxy,
                             float* __restrict__ scoreBuf) {
    __shared__ float red[256];
    __shared__ float cur[5];
    int tid = threadIdx.x;
    for (int s = 0; s < 5; ++s) {
        float sum = 0.f;
        for (int i = tid; i < NBLK; i += 256) sum += partial[i * 5 + s];
        red[tid] = sum;
        __syncthreads();
        for (int off = 128; off > 0; off >>= 1) {
            if (tid < off) red[tid] += red[tid + off];
            __syncthreads();
        }
        if (tid == 0) cur[s] = red[0] * (1.0f / (64.0f * 2.0f * HWSZ));
        __syncthreads();
    }
    if (tid == 0) {
        float impr[5]; float m = 0.f;
        for (int s = 0; s < 5; ++s) { impr[s] = ema_proxy[s] - cur[s]; m += impr[s]; }
        m *= 0.2f;
        for (int s = 0; s < 5; ++s) {
            float adv = impr[s] - m;
            float c = cur[s];
            float below = fmaxf(0.05f - c, 0.f);
            float above = fmaxf(c - 0.2f, 0.f);
            float band = -(below * below + above * above);
            scoreBuf[s] = 1.0f * adv + 0.5f * band;
        }
    }
}

// ---------------- per-pixel softmax over Sn=5
__global__ void softmax_kernel(const float* __restrict__ slearn,
                               const float* __restrict__ scoreBuf,
                               float* __restrict__ out) {
    int i = blockIdx.x * 256 + threadIdx.x;
    if (i >= 2 * HWSZ) return;
    int b = i / HWSZ, p = i % HWSZ;
    float l[5];
    float mx = -1e30f;
    #pragma unroll
    for (int s = 0; s < 5; ++s) {
        float v = (0.5f * scoreBuf[s] + 0.5f * slearn[((size_t)(b * 5 + s)) * HWSZ + p]) / 0.7f;
        l[s] = v;
        mx = fmaxf(mx, v);
    }
    float sum = 0.f;
    #pragma unroll
    for (int s = 0; s < 5; ++s) { l[s] = expf(l[s] - mx); sum += l[s]; }
    float inv = 1.0f / sum;
    #pragma unroll
    for (int s = 0; s < 5; ++s) out[((size_t)(b * 5 + s)) * HWSZ + p] = l[s] * inv;
}

extern "C" void kernel_launch(void* const* d_in, const int* in_sizes, int n_in,
                              void* d_out, int out_size, void* d_ws, size_t ws_size,
                              hipStream_t stream) {
    const float* S   = (const float*)d_in[0];
    const float* T   = (const float*)d_in[1];
    const float* aw  = (const float*)d_in[2];
    const float* ab  = (const float*)d_in[3];
    const float* rw1 = (const float*)d_in[4];
    const float* rb1 = (const float*)d_in[5];
    const float* rw2 = (const float*)d_in[6];
    const float* rb2 = (const float*)d_in[7];
    const float* mu  = (const float*)d_in[8];
    const float* sg  = (const float*)d_in[9];
    const float* ep  = (const float*)d_in[10];

    float* ws = (float*)d_ws;
    float* Dmat     = ws;            // 20480
    float* M_T      = ws + 20480;    // 20480
    float* M_Sp     = ws + 40960;    // 4096
    float* c1       = ws + 45056;    // 64
    float* scoreBuf = ws + 45120;    // 8
    float* partial  = ws + 45184;    // 5760
    float* slearn   = ws + 51200;    // 368640
    float* out = (float*)d_out;

    pre_dmat<<<80, 256, 0, stream>>>(aw, sg, Dmat);
    pre_weights<<<97, 256, 0, stream>>>(rw1, rb1, ab, mu, sg, Dmat, M_T, M_Sp, c1);
    fused_main<<<NBLK, 256, 0, stream>>>(S, T, Dmat, M_T, M_Sp, c1, rw2, rb2, slearn, partial);
    score_kernel<<<1, 256, 0, stream>>>(partial, ep, scoreBuf);
    softmax_kernel<<<288, 256, 0, stream>>>(slearn, scoreBuf, out);
}

// Round 2
// 69.285 us; speedup vs baseline: 3.8056x; 3.8056x over previous
//
#include <hip/hip_runtime.h>
#include <math.h>

#define HWSZ 36864            // 192*192
#define NTILE 576             // HWSZ / 64
#define NBLK 1152             // B * NTILE

typedef short bf16x8 __attribute__((ext_vector_type(8)));
typedef float f32x16 __attribute__((ext_vector_type(16)));
typedef unsigned int u32x4 __attribute__((ext_vector_type(4)));

__device__ __forceinline__ unsigned short f2bf(float x) {
    unsigned u = __float_as_uint(x);
    return (unsigned short)((u + 0x7fffu + ((u >> 16) & 1u)) >> 16);  // RNE
}

// ---------------- precompute 1: Dmat[s][d][c] = adapt_w[s][d][c] / sigma[s][d]
__global__ void pre_dmat(const float* __restrict__ aw, const float* __restrict__ sigma,
                         float* __restrict__ Dmat) {
    int idx = blockIdx.x * 256 + threadIdx.x;
    if (idx < 20480) {
        int sd = idx >> 6;
        Dmat[idx] = aw[idx] / sigma[sd];
    }
}

// ---------------- precompute 2: folded MLP weights
// MT[s][o][c] = sum_d (w1[o,s*192+64+d] + w1[o,s*192+128+d]) * Dmat[s][d][c]
// MSp[o][c]  = sum_{s,d} (w1[o,s*192+d] + w1[o,s*192+64+d]) * Dmat[s][d][c]
// c1[o]      = r_b1[o] + sum_{s,d} (w1[o,s*192+d]+w1[o,s*192+64+d])*(ab[s,d]-mu[s,d])/sigma[s,d]
__global__ void pre_weights(const float* __restrict__ rw1, const float* __restrict__ rb1,
                            const float* __restrict__ ab, const float* __restrict__ mu,
                            const float* __restrict__ sigma, const float* __restrict__ Dmat,
                            float* __restrict__ MT, float* __restrict__ MSp,
                            float* __restrict__ c1) {
    int idx = blockIdx.x * 256 + threadIdx.x;
    if (idx < 20480) {
        int s = idx / 4096, r = idx % 4096, o = r >> 6, c = r & 63;
        float sum = 0.f;
        const float* wp = rw1 + o * 960 + s * 192;
        const float* D  = Dmat + s * 4096 + c;
        #pragma unroll 8
        for (int d = 0; d < 64; ++d)
            sum = fmaf(wp[64 + d] + wp[128 + d], D[d * 64], sum);
        MT[idx] = sum;                     // MT[s*4096 + o*64 + c]
    } else if (idx < 24576) {
        int k = idx - 20480;
        int o = k >> 6, c = k & 63;
        float sum = 0.f;
        for (int s = 0; s < 5; ++s) {
            const float* wp = rw1 + o * 960 + s * 192;
            const float* D  = Dmat + s * 4096 + c;
            #pragma unroll 8
            for (int d = 0; d < 64; ++d)
                sum = fmaf(wp[d] + wp[64 + d], D[d * 64], sum);
        }
        MSp[k] = sum;
    } else if (idx < 24640) {
        int o = idx - 24576;
        float sum = rb1[o];
        for (int s = 0; s < 5; ++s) {
            const float* wp = rw1 + o * 960 + s * 192;
            #pragma unroll 8
            for (int d = 0; d < 64; ++d) {
                int sd = s * 64 + d;
                sum = fmaf(wp[d] + wp[64 + d], (ab[sd] - mu[sd]) / sigma[sd], sum);
            }
        }
        c1[o] = sum;
    }
}

// ---------------- precompute 3: pack A-fragments (bf16) in MFMA 32x32x16 order
// AfragW layout [s][r(4)][t(4)][lane(64)][e(8)]; rows r<2 = D_s, r>=2 = MT_s
// AfragSp layout [r(2)][t(4)][lane(64)][e(8)] of MSp
__global__ void pre_pack(const float* __restrict__ Dmat, const float* __restrict__ MT,
                         const float* __restrict__ MSp,
                         unsigned short* __restrict__ AfragW,
                         unsigned short* __restrict__ AfragSp) {
    int i = blockIdx.x * 256 + threadIdx.x;
    if (i < 40960) {
        int s = i / 8192, rem = i % 8192;
        int r = rem / 2048, rem2 = rem % 2048;
        int t = rem2 / 512, q = rem2 % 512;
        int l = q >> 3, e = q & 7;
        int R = 32 * r + (l & 31);
        int k = 16 * t + 8 * (l >> 5) + e;
        float v = (R < 64) ? Dmat[s * 4096 + R * 64 + k] : MT[s * 4096 + (R - 64) * 64 + k];
        AfragW[i] = f2bf(v);
    } else if (i < 45056) {
        int j = i - 40960;
        int r = j / 2048, rem2 = j % 2048;
        int t = rem2 / 512, q = rem2 % 512;
        int l = q >> 3, e = q & 7;
        float v = MSp[(32 * r + (l & 31)) * 64 + 16 * t + 8 * (l >> 5) + e];
        AfragSp[j] = f2bf(v);
    }
}

// ---------------- fused main (MFMA): per 64-pixel tile
__global__ __launch_bounds__(256) void fused_main(
        const float* __restrict__ S, const float* __restrict__ T,
        const unsigned short* __restrict__ AfragW, const unsigned short* __restrict__ AfragSp,
        const float* __restrict__ c1, const float* __restrict__ rw2, const float* __restrict__ rb2,
        float* __restrict__ slearn, float* __restrict__ partial) {
    __shared__ __align__(16) unsigned short Xb[4096];   // (T_s - S) bf16, [c][pix]
    __shared__ __align__(16) unsigned short Sb[4096];   // S bf16, [c][pix]
    __shared__ float hbuf[64][64];                      // h / relu(h)
    __shared__ float wred[5][2];
    __shared__ float c1s[64];

    const int tid  = threadIdx.x;
    const int lane = tid & 63;
    const int w    = tid >> 6;        // wave id 0..3
    const int blk  = blockIdx.x;
    const int b    = blk / NTILE;
    const int pix0 = (blk % NTILE) * 64;

    const int hi = lane >> 5;         // k-half for MFMA frags
    const int px = lane & 31;         // col within 32-tile

    if (tid < 64) c1s[tid] = c1[tid];

    // ---- stage Sb (all threads) ----
    {
        const int pg = tid & 7, c0 = tid >> 3;
        for (int it = 0; it < 2; ++it) {
            int c = c0 + 32 * it;
            const float* Sp = S + ((size_t)(b * 64 + c)) * HWSZ + pix0 + pg * 8;
            float4 s0 = *(const float4*)Sp;
            float4 s1 = *(const float4*)(Sp + 4);
            u32x4 o;
            o.x = f2bf(s0.x) | ((unsigned)f2bf(s0.y) << 16);
            o.y = f2bf(s0.z) | ((unsigned)f2bf(s0.w) << 16);
            o.z = f2bf(s1.x) | ((unsigned)f2bf(s1.y) << 16);
            o.w = f2bf(s1.z) | ((unsigned)f2bf(s1.w) << 16);
            *(u32x4*)&Sb[c * 64 + pg * 8] = o;
        }
    }
    __syncthreads();

    auto stage_row = [&](int s, int c, int pg) {
        const float* Tp = T + ((size_t)((b * 5 + s) * 64 + c)) * HWSZ + pix0 + pg * 8;
        const float* Sp = S + ((size_t)(b * 64 + c)) * HWSZ + pix0 + pg * 8;
        float4 t0 = *(const float4*)Tp;
        float4 t1 = *(const float4*)(Tp + 4);
        float4 s0 = *(const float4*)Sp;
        float4 s1 = *(const float4*)(Sp + 4);
        u32x4 o;
        o.x = f2bf(t0.x - s0.x) | ((unsigned)f2bf(t0.y - s0.y) << 16);
        o.y = f2bf(t0.z - s0.z) | ((unsigned)f2bf(t0.w - s0.w) << 16);
        o.z = f2bf(t1.x - s1.x) | ((unsigned)f2bf(t1.y - s1.y) << 16);
        o.w = f2bf(t1.z - s1.z) | ((unsigned)f2bf(t1.w - s1.w) << 16);
        *(u32x4*)&Xb[c * 64 + pg * 8] = o;
    };

    auto run_gemm = [&](const unsigned short* afr, int fragblk, const unsigned short* lds,
                        f32x16& accA, f32x16& accB) {
        const bf16x8* ap = reinterpret_cast<const bf16x8*>(afr) + (size_t)fragblk * 256 + lane;
        bf16x8 Af[4];
        #pragma unroll
        for (int kt = 0; kt < 4; ++kt) Af[kt] = ap[kt * 64];
        #pragma unroll
        for (int kt = 0; kt < 4; ++kt) {
            bf16x8 Bq;
            int base = (kt * 16 + hi * 8) * 64 + px;
            #pragma unroll
            for (int e = 0; e < 8; ++e) Bq[e] = (short)lds[base + e * 64];
            accA = __builtin_amdgcn_mfma_f32_32x32x16_bf16(Af[kt], Bq, accA, 0, 0, 0);
        }
        #pragma unroll
        for (int kt = 0; kt < 4; ++kt) {
            bf16x8 Bq;
            int base = (kt * 16 + hi * 8) * 64 + px + 32;
            #pragma unroll
            for (int e = 0; e < 8; ++e) Bq[e] = (short)lds[base + e * 64];
            accB = __builtin_amdgcn_mfma_f32_32x32x16_bf16(Af[kt], Bq, accB, 0, 0, 0);
        }
    };

    f32x16 acc0, acc1;
    #pragma unroll
    for (int i = 0; i < 16; ++i) { acc0[i] = 0.f; acc1[i] = 0.f; }

    if (w < 2) {
        // M_Sp @ S, rowtile w; write raw partial h to hbuf, then regs are reused for delta
        run_gemm(AfragSp, w, Sb, acc0, acc1);
        #pragma unroll
        for (int i = 0; i < 16; ++i) {
            int row = (i & 3) + 8 * (i >> 2) + 4 * hi + 32 * w;
            hbuf[row][px]      = acc0[i];
            hbuf[row][px + 32] = acc1[i];
        }
    } else {
        // waves 2,3: stage X_0
        int t2 = tid - 128;
        int pg = t2 & 7, cb = t2 >> 3;
        for (int it = 0; it < 4; ++it) stage_row(0, cb + 16 * it, pg);
    }
    __syncthreads();

    for (int s = 0; s < 5; ++s) {
        if (w < 2) {
            #pragma unroll
            for (int i = 0; i < 16; ++i) { acc0[i] = 0.f; acc1[i] = 0.f; }
        }
        // waves 0,1: delta rows (r=w); waves 2,3: h rows (r=w) of combined [D_s; MT_s]
        run_gemm(AfragW, s * 4 + w, Xb, acc0, acc1);
        if (w < 2) {
            float sq = 0.f;
            #pragma unroll
            for (int i = 0; i < 16; ++i) {
                sq = fmaf(acc0[i], acc0[i], sq);
                sq = fmaf(acc1[i], acc1[i], sq);
            }
            #pragma unroll
            for (int m = 1; m < 64; m <<= 1) sq += __shfl_xor(sq, m, 64);
            if (lane == 0) wred[s][w] = sq;
        }
        __syncthreads();
        if (s < 4) {
            int pg = tid & 7, c0 = tid >> 3;
            stage_row(s + 1, c0, pg);
            stage_row(s + 1, c0 + 32, pg);
            __syncthreads();
        }
    }

    if (w >= 2) {
        #pragma unroll
        for (int i = 0; i < 16; ++i) {
            int row = (i & 3) + 8 * (i >> 2) + 4 * hi + 32 * (w - 2);
            float v0 = hbuf[row][px]      + acc0[i] + c1s[row];
            float v1 = hbuf[row][px + 32] + acc1[i] + c1s[row];
            hbuf[row][px]      = fmaxf(v0, 0.f);
            hbuf[row][px + 32] = fmaxf(v1, 0.f);
        }
    }
    __syncthreads();

    // score_learn = r_w2 @ relu(h) + r_b2
    {
        int p = tid & 63;
        for (int sp = w; sp < 5; sp += 4) {
            float sum = rb2[sp];
            #pragma unroll 8
            for (int o = 0; o < 64; ++o) sum = fmaf(rw2[sp * 64 + o], hbuf[o][p], sum);
            slearn[((size_t)(b * 5 + sp)) * HWSZ + pix0 + p] = sum;
        }
    }
    if (tid < 5) partial[blk * 5 + tid] = wred[tid][0] + wred[tid][1];
}

// ---------------- reduce proxy partials -> per-s score (deterministic)
__global__ void score_kernel(const float* __restrict__ partial,
                             const float* __restrict__ ema_proxy,
                             float* __restrict__ scoreBuf) {
    __shared__ float red[256];
    __shared__ float cur[5];
    int tid = threadIdx.x;
    for (int s = 0; s < 5; ++s) {
        float sum = 0.f;
        for (int i = tid; i < NBLK; i += 256) sum += partial[i * 5 + s];
        red[tid] = sum;
        __syncthreads();
        for (int off = 128; off > 0; off >>= 1) {
            if (tid < off) red[tid] += red[tid + off];
            __syncthreads();
        }
        if (tid == 0) cur[s] = red[0] * (1.0f / (64.0f * 2.0f * HWSZ));
        __syncthreads();
    }
    if (tid == 0) {
        float impr[5]; float m = 0.f;
        for (int s = 0; s < 5; ++s) { impr[s] = ema_proxy[s] - cur[s]; m += impr[s]; }
        m *= 0.2f;
        for (int s = 0; s < 5; ++s) {
            float adv = impr[s] - m;
            float c = cur[s];
            float below = fmaxf(0.05f - c, 0.f);
            float above = fmaxf(c - 0.2f, 0.f);
            float band = -(below * below + above * above);
            scoreBuf[s] = 1.0f * adv + 0.5f * band;
        }
    }
}

// ---------------- per-pixel softmax over Sn=5
__global__ void softmax_kernel(const float* __restrict__ slearn,
                               const float* __restrict__ scoreBuf,
                               float* __restrict__ out) {
    int i = blockIdx.x * 256 + threadIdx.x;
    if (i >= 2 * HWSZ) return;
    int b = i / HWSZ, p = i % HWSZ;
    float l[5];
    float mx = -1e30f;
    #pragma unroll
    for (int s = 0; s < 5; ++s) {
        float v = (0.5f * scoreBuf[s] + 0.5f * slearn[((size_t)(b * 5 + s)) * HWSZ + p]) / 0.7f;
        l[s] = v;
        mx = fmaxf(mx, v);
    }
    float sum = 0.f;
    #pragma unroll
    for (int s = 0; s < 5; ++s) { l[s] = expf(l[s] - mx); sum += l[s]; }
    float inv = 1.0f / sum;
    #pragma unroll
    for (int s = 0; s < 5; ++s) out[((size_t)(b * 5 + s)) * HWSZ + p] = l[s] * inv;
}

extern "C" void kernel_launch(void* const* d_in, const int* in_sizes, int n_in,
                              void* d_out, int out_size, void* d_ws, size_t ws_size,
                              hipStream_t stream) {
    const float* S   = (const float*)d_in[0];
    const float* T   = (const float*)d_in[1];
    const float* aw  = (const float*)d_in[2];
    const float* ab  = (const float*)d_in[3];
    const float* rw1 = (const float*)d_in[4];
    const float* rb1 = (const float*)d_in[5];
    const float* rw2 = (const float*)d_in[6];
    const float* rb2 = (const float*)d_in[7];
    const float* mu  = (const float*)d_in[8];
    const float* sg  = (const float*)d_in[9];
    const float* ep  = (const float*)d_in[10];

    float* ws = (float*)d_ws;
    // persistent within launch:
    float* c1f      = ws;             // 0    .. 64
    float* scoreBuf = ws + 64;        // 64   .. 72
    float* partial  = ws + 72;        // 72   .. 5832
    unsigned short* AfragW  = (unsigned short*)(ws + 5832);   // 40960 ush = 20480 f
    unsigned short* AfragSp = (unsigned short*)(ws + 26312);  // 4096 ush = 2048 f
    float* slearn   = ws + 28360;     // 28360 .. 397000
    // transient (dead before slearn is written) — aliased inside slearn region:
    float* Dmat     = ws + 28360;     // 20480
    float* MT       = ws + 48840;     // 20480
    float* MSp      = ws + 69320;     // 4096
    float* out = (float*)d_out;

    pre_dmat<<<80, 256, 0, stream>>>(aw, sg, Dmat);
    pre_weights<<<97, 256, 0, stream>>>(rw1, rb1, ab, mu, sg, Dmat, MT, MSp, c1f);
    pre_pack<<<176, 256, 0, stream>>>(Dmat, MT, MSp, AfragW, AfragSp);
    fused_main<<<NBLK, 256, 0, stream>>>(S, T, AfragW, AfragSp, c1f, rw2, rb2, slearn, partial);
    score_kernel<<<1, 256, 0, stream>>>(partial, ep, scoreBuf);
    softmax_kernel<<<288, 256, 0, stream>>>(slearn, scoreBuf, out);
}